// Round 3
// baseline (27112.433 us; speedup 1.0000x reference)
//
#include <hip/hip_runtime.h>

// Problem constants
#define HH    1024
#define DD    256
#define BSB   1024
#define TT    256
#define N3H   3072   // 3*H
#define CAT1  32
#define CAT2E 47

typedef unsigned short u16;
typedef short bf16x8 __attribute__((ext_vector_type(8)));
typedef float f32x4  __attribute__((ext_vector_type(4)));

__device__ __forceinline__ u16 f2bf(float f) {
  unsigned int x = __float_as_uint(f);
  unsigned int lsb = (x >> 16) & 1u;
  x += 0x7fffu + lsb;
  return (u16)(x >> 16);
}

// async global->LDS, 16B per lane; LDS dest is wave-uniform base + lane*16
__device__ __forceinline__ void gload_lds16(const u16* src, u16* lds) {
  __builtin_amdgcn_global_load_lds(
      (const __attribute__((address_space(1))) void*)src,
      (__attribute__((address_space(3))) void*)lds, 16, 0, 0);
}

// ---------------------------------------------------------------------------
// Plain GEMM: C[M,N] = A[M,K] @ B[N,K]^T (+bias) (+addend); optional fused
// head activation (act=1). Tile 128x128, BK=64, 4 waves, 2-deep dbuf pipeline
// with counted vmcnt. LDS passed in (64 KiB region).
// mfma_f32_16x16x32_bf16 layouts (HW-verified m89/m91):
//   A frag: A[m=lane&15][k=(lane>>4)*8+j];  B frag: W[n=lane&15][k=(lane>>4)*8+j]
//   C/D:    col=lane&15, row=(lane>>4)*4+reg
// ---------------------------------------------------------------------------
struct GArg {
  const u16* A; int lda; int K;
  const u16* B; int ldb; int N;
  float* C; int ldc;
  const float* bias;
  const float* addend;
  float* out;           // act: output tensor
  u16* xout;            // act: bf16 next-x
  int tstep;
  int act;
};

#define BM 128
#define BN 128
#define BK 64

__device__ void plain_gemm_body(const GArg& g, u16* lds)
{
  const int colBase = blockIdx.x * BN;
  if (colBase >= g.N) return;
  const int rowBase = blockIdx.y * BM;

  u16* As = lds;            // [2][128*64]
  u16* Bs = lds + 16384;    // [2][128*64]

  const int tid  = threadIdx.x;
  const int wave = tid >> 6;
  const int lane = tid & 63;
  const int q    = lane >> 4;
  const int l16  = lane & 15;
  const int waveRow = (wave >> 1) * 64;
  const int waveCol = (wave & 1) * 64;

  const int  srow = wave * 8 + (lane >> 3);
  const int  sswz = ((lane & 7) ^ (lane >> 3)) << 3;
  const u16* aptr = g.A + (size_t)(rowBase + srow) * g.lda + sswz;
  const u16* bptr = g.B + (size_t)(colBase + srow) * g.ldb + sswz;
  const size_t astep = (size_t)32 * g.lda;
  const size_t bstep = (size_t)32 * g.ldb;
  const int ldoff = wave << 9;

  f32x4 acc[4][4];
  #pragma unroll
  for (int i = 0; i < 4; ++i)
    #pragma unroll
    for (int j = 0; j < 4; ++j)
      acc[i][j] = (f32x4){0.f, 0.f, 0.f, 0.f};

  const int nk = g.K >> 6;

  #pragma unroll
  for (int i = 0; i < 4; ++i) {
    gload_lds16(aptr + (size_t)i * astep, &As[ldoff + (i << 11)]);
    gload_lds16(bptr + (size_t)i * bstep, &Bs[ldoff + (i << 11)]);
  }
  #pragma unroll
  for (int i = 0; i < 4; ++i) {
    gload_lds16(aptr + 64 + (size_t)i * astep, &As[8192 + ldoff + (i << 11)]);
    gload_lds16(bptr + 64 + (size_t)i * bstep, &Bs[8192 + ldoff + (i << 11)]);
  }

  for (int k = 0; k < nk; ++k) {
    const int cb = (k & 1) << 13;   // buf elem offset
    if (k < nk - 1) {
      asm volatile("s_waitcnt vmcnt(8)" ::: "memory");
    } else {
      asm volatile("s_waitcnt vmcnt(0)" ::: "memory");
    }
    __builtin_amdgcn_s_barrier();
    __builtin_amdgcn_sched_barrier(0);

    #pragma unroll
    for (int ks = 0; ks < 2; ++ks) {
      bf16x8 af[4], bfr[4];
      const int kb = (ks << 2) + q;
      #pragma unroll
      for (int mi = 0; mi < 4; ++mi) {
        int r = waveRow + mi * 16 + l16;
        af[mi] = *(const bf16x8*)&As[cb + (r << 6) + ((kb ^ (l16 & 7)) << 3)];
      }
      #pragma unroll
      for (int ni = 0; ni < 4; ++ni) {
        int r = waveCol + ni * 16 + l16;
        bfr[ni] = *(const bf16x8*)&Bs[cb + (r << 6) + ((kb ^ (l16 & 7)) << 3)];
      }
      #pragma unroll
      for (int mi = 0; mi < 4; ++mi)
        #pragma unroll
        for (int ni = 0; ni < 4; ++ni)
          acc[mi][ni] = __builtin_amdgcn_mfma_f32_16x16x32_bf16(af[mi], bfr[ni], acc[mi][ni], 0, 0, 0);
    }

    __builtin_amdgcn_sched_barrier(0);
    __builtin_amdgcn_s_barrier();
    __builtin_amdgcn_sched_barrier(0);
    if (k + 2 < nk) {
      const int k2 = (k + 2) << 6;
      #pragma unroll
      for (int i = 0; i < 4; ++i) {
        gload_lds16(aptr + k2 + (size_t)i * astep, &As[cb + ldoff + (i << 11)]);
        gload_lds16(bptr + k2 + (size_t)i * bstep, &Bs[cb + ldoff + (i << 11)]);
      }
    }
  }

  if (g.act) {
    const bool smWave = (colBase + waveCol) == 0;
    #pragma unroll
    for (int mi = 0; mi < 4; ++mi) {
      #pragma unroll
      for (int r = 0; r < 4; ++r) {
        const int row = rowBase + waveRow + mi * 16 + q * 4 + r;
        float v[4];
        #pragma unroll
        for (int ni = 0; ni < 4; ++ni)
          v[ni] = acc[mi][ni][r] + g.bias[colBase + waveCol + ni * 16 + l16];
        float res[4];
        if (smWave) {
          float m1 = fmaxf(v[0], v[1]);
          #pragma unroll
          for (int msk = 1; msk < 16; msk <<= 1) m1 = fmaxf(m1, __shfl_xor(m1, msk));
          float e0 = expf(v[0] - m1), e1 = expf(v[1] - m1);
          float s1 = e0 + e1;
          #pragma unroll
          for (int msk = 1; msk < 16; msk <<= 1) s1 += __shfl_xor(s1, msk);
          res[0] = e0 / s1;
          res[1] = e1 / s1;
          float mv = (l16 < 15) ? v[2] : -1e30f;
          #pragma unroll
          for (int msk = 1; msk < 16; msk <<= 1) mv = fmaxf(mv, __shfl_xor(mv, msk));
          float e2 = expf(v[2] - mv);
          float sv = (l16 < 15) ? e2 : 0.f;
          #pragma unroll
          for (int msk = 1; msk < 16; msk <<= 1) sv += __shfl_xor(sv, msk);
          res[2] = (l16 < 15) ? (e2 / sv) : (1.f / (1.f + expf(-v[2])));
          res[3] = 1.f / (1.f + expf(-v[3]));
        } else {
          #pragma unroll
          for (int ni = 0; ni < 4; ++ni)
            res[ni] = 1.f / (1.f + expf(-v[ni]));
        }
        #pragma unroll
        for (int ni = 0; ni < 4; ++ni) {
          const int col = colBase + waveCol + ni * 16 + l16;
          g.out[((size_t)row * TT + g.tstep) * DD + col] = res[ni];
          g.xout[row * DD + col] = f2bf(res[ni]);
        }
      }
    }
    return;
  }

  #pragma unroll
  for (int mi = 0; mi < 4; ++mi) {
    #pragma unroll
    for (int ni = 0; ni < 4; ++ni) {
      #pragma unroll
      for (int r = 0; r < 4; ++r) {
        int row = rowBase + waveRow + mi * 16 + q * 4 + r;
        int col = colBase + waveCol + ni * 16 + l16;
        float v = acc[mi][ni][r];
        if (g.bias)   v += g.bias[col];
        if (g.addend) v += g.addend[(size_t)row * g.ldc + col];
        g.C[(size_t)row * g.ldc + col] = v;
      }
    }
  }
}

// ---------------------------------------------------------------------------
// Fused gate-GEMM: block = 128 batch rows x 64 hidden units x 3 gates.
// Computes gi_{r,z,n} = A @ W[g*1024+u]^T (+bias3/+Gadd), reads precomputed
// gh_{r,z,n} from GH, applies GRU gate, writes h (fp32) + hbf.
// Grid x in [0,16) (uBase = x*64), y in [0,8). Wave w owns rows w*32..+32.
// LDS (80 KiB): A [2][128*64] @0, B [2][3][64*64] @16384.
// ---------------------------------------------------------------------------
struct FArg {
  const u16* A; int lda; int K;    // activations (xbf or h0b)
  const u16* W; int ldw;           // weight, rows g*1024 + unit
  const float* Gadd;               // per-(row,3H-col) addend (Gglob) or null
  const float* bias3;              // 3H bias (b_ih1) or null
  const float* GH;                 // precomputed gh (row,3H), includes b_hh
  float* hf; u16* hb;              // state: read old h, write new
};

__device__ void fused_gate_body(const FArg& f, u16* lds)
{
  if (blockIdx.x >= 16) return;
  const int uBase   = blockIdx.x * 64;
  const int rowBase = blockIdx.y * 128;

  const int tid  = threadIdx.x;
  const int wave = tid >> 6;
  const int lane = tid & 63;
  const int q    = lane >> 4;
  const int l16  = lane & 15;

  const int  srow = wave * 8 + (lane >> 3);
  const int  sswz = ((lane & 7) ^ (lane >> 3)) << 3;
  const u16* aptr = f.A + (size_t)(rowBase + srow) * f.lda + sswz;
  const u16* wp0  = f.W + (size_t)(uBase + srow) * f.ldw + sswz;
  const u16* wp1  = f.W + (size_t)(1024 + uBase + srow) * f.ldw + sswz;
  const u16* wp2  = f.W + (size_t)(2048 + uBase + srow) * f.ldw + sswz;
  const size_t astep = (size_t)32 * f.lda;
  const size_t wstep = (size_t)32 * f.ldw;
  const int ldoff = wave << 9;   // wave-uniform 512-elem offset

  f32x4 acc[2][4][3];
  #pragma unroll
  for (int ri = 0; ri < 2; ++ri)
    #pragma unroll
    for (int ci = 0; ci < 4; ++ci)
      #pragma unroll
      for (int gg = 0; gg < 3; ++gg)
        acc[ri][ci][gg] = (f32x4){0.f, 0.f, 0.f, 0.f};

  const int nk = f.K >> 6;

  // stage tile t into buffer buf (10 loads/thread: 4 A + 6 B)
  auto stage = [&](int buf, int k0) {
    const int ab = buf * 8192;
    const int bb = 16384 + buf * 12288;
    #pragma unroll
    for (int i = 0; i < 4; ++i)
      gload_lds16(aptr + k0 + (size_t)i * astep, &lds[ab + ldoff + (i << 11)]);
    #pragma unroll
    for (int i = 0; i < 2; ++i) {
      gload_lds16(wp0 + k0 + (size_t)i * wstep, &lds[bb +         ldoff + (i << 11)]);
      gload_lds16(wp1 + k0 + (size_t)i * wstep, &lds[bb + 4096 +  ldoff + (i << 11)]);
      gload_lds16(wp2 + k0 + (size_t)i * wstep, &lds[bb + 8192 +  ldoff + (i << 11)]);
    }
  };

  stage(0, 0);
  stage(1, 64);

  for (int k = 0; k < nk; ++k) {
    const int buf = k & 1;
    const int ab = buf * 8192;
    const int bb = 16384 + buf * 12288;
    if (k < nk - 1) {
      asm volatile("s_waitcnt vmcnt(10)" ::: "memory");
    } else {
      asm volatile("s_waitcnt vmcnt(0)" ::: "memory");
    }
    __builtin_amdgcn_s_barrier();
    __builtin_amdgcn_sched_barrier(0);

    #pragma unroll
    for (int ks = 0; ks < 2; ++ks) {
      const int kb = (ks << 2) + q;
      const int ksw = (kb ^ (l16 & 7)) << 3;
      bf16x8 a[2];
      #pragma unroll
      for (int ri = 0; ri < 2; ++ri) {
        int r = wave * 32 + ri * 16 + l16;
        a[ri] = *(const bf16x8*)&lds[ab + (r << 6) + ksw];
      }
      #pragma unroll
      for (int gg = 0; gg < 3; ++gg) {
        bf16x8 b[4];
        #pragma unroll
        for (int ci = 0; ci < 4; ++ci) {
          int r = ci * 16 + l16;
          b[ci] = *(const bf16x8*)&lds[bb + gg * 4096 + (r << 6) + ksw];
        }
        #pragma unroll
        for (int ri = 0; ri < 2; ++ri)
          #pragma unroll
          for (int ci = 0; ci < 4; ++ci)
            acc[ri][ci][gg] = __builtin_amdgcn_mfma_f32_16x16x32_bf16(a[ri], b[ci], acc[ri][ci][gg], 0, 0, 0);
      }
    }

    __builtin_amdgcn_sched_barrier(0);
    __builtin_amdgcn_s_barrier();
    __builtin_amdgcn_sched_barrier(0);
    if (k + 2 < nk) stage(buf, (k + 2) << 6);
  }

  // gate epilogue
  #pragma unroll
  for (int ri = 0; ri < 2; ++ri) {
    #pragma unroll
    for (int ci = 0; ci < 4; ++ci) {
      #pragma unroll
      for (int rr = 0; rr < 4; ++rr) {
        const int row  = rowBase + wave * 32 + ri * 16 + q * 4 + rr;
        const int unit = uBase + ci * 16 + l16;
        const size_t c0 = (size_t)row * N3H + unit;
        float gi0 = acc[ri][ci][0][rr];
        float gi1 = acc[ri][ci][1][rr];
        float gi2 = acc[ri][ci][2][rr];
        if (f.bias3) {
          gi0 += f.bias3[unit];
          gi1 += f.bias3[1024 + unit];
          gi2 += f.bias3[2048 + unit];
        }
        if (f.Gadd) {
          gi0 += f.Gadd[c0];
          gi1 += f.Gadd[c0 + 1024];
          gi2 += f.Gadd[c0 + 2048];
        }
        const float gh0 = f.GH[c0];
        const float gh1 = f.GH[c0 + 1024];
        const float gh2 = f.GH[c0 + 2048];
        const float rg = 1.f / (1.f + expf(-(gi0 + gh0)));
        const float zg = 1.f / (1.f + expf(-(gi1 + gh1)));
        const float ng = tanhf(gi2 + rg * gh2);
        const int hidx = row * HH + unit;
        const float hv = f.hf[hidx];
        const float hn = (1.f - zg) * ng + zg * hv;
        f.hf[hidx] = hn;
        f.hb[hidx] = f2bf(hn);
      }
    }
  }
}

// step kernel: z0 = fused gate-GEMM, z1 = plain GEMM (80 KiB LDS union)
__global__ __launch_bounds__(256, 2) void step_kernel(FArg fa, GArg gb)
{
  __shared__ __align__(16) u16 lds[40960];
  if (blockIdx.z == 0) fused_gate_body(fa, lds);
  else                 plain_gemm_body(gb, lds);
}

// plain/act pair kernel (64 KiB LDS) — prologue + L_C
__global__ __launch_bounds__(256, 2) void gemm_bt4(GArg ga, GArg gb)
{
  __shared__ __align__(16) u16 lds[32768];
  plain_gemm_body(blockIdx.z == 0 ? ga : gb, lds);
}

// ---------------------------------------------------------------------------
// Prep: fp32 -> bf16 weight conversion; state init
// ---------------------------------------------------------------------------
__global__ void convert_kernel(const float* __restrict__ src, u16* __restrict__ dst, int n)
{
  int i = blockIdx.x * blockDim.x + threadIdx.x;
  if (i < n) dst[i] = f2bf(src[i]);
}

__global__ void prep_state(const float* __restrict__ embed, const float* __restrict__ dyn,
                           u16* __restrict__ globbf,
                           float* __restrict__ h0, u16* __restrict__ h0bf,
                           float* __restrict__ h1, u16* __restrict__ h1bf,
                           u16* __restrict__ xbf)
{
  int idx = blockIdx.x * blockDim.x + threadIdx.x;  // 1M
  int b = idx >> 10, j = idx & 1023;
  const float* e = embed + (size_t)b * 3072;
  globbf[idx] = f2bf(e[j]);
  float v0 = e[1024 + j]; h0[idx] = v0; h0bf[idx] = f2bf(v0);
  float v1 = e[2048 + j]; h1[idx] = v1; h1bf[idx] = f2bf(v1);
  if (j < DD) {
    xbf[b * DD + j] = f2bf(dyn[(size_t)b * (TT * DD) + j]);  // x0
  }
}

// ---------------------------------------------------------------------------
extern "C" void kernel_launch(void* const* d_in, const int* in_sizes, int n_in,
                              void* d_out, int out_size, void* d_ws, size_t ws_size,
                              hipStream_t stream)
{
  const float* embed = (const float*)d_in[0];
  const float* dyn   = (const float*)d_in[1];
  // d_in[2] = seq_len (256, hardcoded)
  const float* W_ih0 = (const float*)d_in[3];
  const float* W_hh0 = (const float*)d_in[4];
  const float* b_ih0 = (const float*)d_in[5];
  const float* b_hh0 = (const float*)d_in[6];
  const float* W_ih1 = (const float*)d_in[7];
  const float* W_hh1 = (const float*)d_in[8];
  const float* b_ih1 = (const float*)d_in[9];
  const float* b_hh1 = (const float*)d_in[10];
  const float* W_fc  = (const float*)d_in[11];
  const float* b_fc  = (const float*)d_in[12];
  float* out = (float*)d_out;

  char* ws = (char*)d_ws;
  size_t off = 0;
  auto carve = [&](size_t bytes) -> void* {
    void* p = ws + off;
    off += (bytes + 255) & ~(size_t)255;
    return p;
  };
  u16* Wih0b = (u16*)carve((size_t)N3H * 1280 * 2);
  u16* Whh0b = (u16*)carve((size_t)N3H * HH * 2);
  u16* Wih1b = (u16*)carve((size_t)N3H * HH * 2);
  u16* Whh1b = (u16*)carve((size_t)N3H * HH * 2);
  u16* Wfcb  = (u16*)carve((size_t)DD * HH * 2);
  u16* globb = (u16*)carve((size_t)BSB * HH * 2);
  u16* xbf   = (u16*)carve((size_t)BSB * DD * 2);
  float* h0f = (float*)carve((size_t)BSB * HH * 4);
  float* h1f = (float*)carve((size_t)BSB * HH * 4);
  u16* h0b   = (u16*)carve((size_t)BSB * HH * 2);
  u16* h1b   = (u16*)carve((size_t)BSB * HH * 2);
  float* Gglob  = (float*)carve((size_t)BSB * N3H * 4);
  float* GH0f   = (float*)carve((size_t)BSB * N3H * 4);
  float* GH1f   = (float*)carve((size_t)BSB * N3H * 4);
  (void)ws_size;

  {
    int n;
    n = N3H * 1280; convert_kernel<<<(n + 255) / 256, 256, 0, stream>>>(W_ih0, Wih0b, n);
    n = N3H * HH;   convert_kernel<<<(n + 255) / 256, 256, 0, stream>>>(W_hh0, Whh0b, n);
    n = N3H * HH;   convert_kernel<<<(n + 255) / 256, 256, 0, stream>>>(W_ih1, Wih1b, n);
    n = N3H * HH;   convert_kernel<<<(n + 255) / 256, 256, 0, stream>>>(W_hh1, Whh1b, n);
    n = DD * HH;    convert_kernel<<<(n + 255) / 256, 256, 0, stream>>>(W_fc, Wfcb, n);
  }
  prep_state<<<(BSB * HH) / 256, 256, 0, stream>>>(embed, dyn, globb, h0f, h0b, h1f, h1b, xbf);

  // --- prologue ---
  {  // Gglob = glob @ W_ih0[:, :H]^T + b_ih0
    GArg g{globb, HH, HH, Wih0b, 1280, N3H, Gglob, N3H, b_ih0, nullptr, nullptr, nullptr, 0, 0};
    gemm_bt4<<<dim3(24, 8, 1), 256, 0, stream>>>(g, g);
  }
  {  // GH0(0) = h0 @ W_hh0^T + b_hh0 ; GH1(0) = h1 @ W_hh1^T + b_hh1
    GArg ga{h0b, HH, HH, Whh0b, HH, N3H, GH0f, N3H, b_hh0, nullptr, nullptr, nullptr, 0, 0};
    GArg gb{h1b, HH, HH, Whh1b, HH, N3H, GH1f, N3H, b_hh1, nullptr, nullptr, nullptr, 0, 0};
    gemm_bt4<<<dim3(24, 8, 2), 256, 0, stream>>>(ga, gb);
  }

  const GArg gnull{nullptr, 0, 64, nullptr, 0, 0, nullptr, 0,
                   nullptr, nullptr, nullptr, nullptr, 0, 0};  // N=0 -> exit

  // --- T sequential steps (3 launches each) ---
  for (int t = 0; t < TT; ++t) {
    bool last = (t == TT - 1);

    {  // L_A: gi0 = x@Wih0x^T + Gglob ; gate0 with GH0 -> h0
      FArg fa{xbf, DD, DD, Wih0b + HH, 1280, Gglob, nullptr, GH0f, h0f, h0b};
      step_kernel<<<dim3(16, 8, 1), 256, 0, stream>>>(fa, gnull);
    }

    {  // L_B: z0 = gi1 = h0n@Wih1^T + b_ih1, gate1 with GH1 -> h1
       //      z1 = GH0(t+1) = h0n@Whh0^T + b_hh0
      FArg fa{h0b, HH, HH, Wih1b, HH, nullptr, b_ih1, GH1f, h1f, h1b};
      GArg gh{h0b, HH, HH, Whh0b, HH, N3H, GH0f, N3H, b_hh0, nullptr, nullptr, nullptr, 0, 0};
      step_kernel<<<last ? dim3(16, 8, 1) : dim3(24, 8, 2), 256, 0, stream>>>(fa, gh);
    }

    {  // L_C: z0 = head+act -> out[:,t,:], xbf ; z1 = GH1(t+1) = h1n@Whh1^T + b_hh1
      GArg gc{h1b, HH, HH, Wfcb, HH, DD, nullptr, DD, b_fc, nullptr, out, xbf, t, 1};
      GArg gh{h1b, HH, HH, Whh1b, HH, N3H, GH1f, N3H, b_hh1, nullptr, nullptr, nullptr, 0, 0};
      gemm_bt4<<<last ? dim3(2, 8, 1) : dim3(24, 8, 2), 256, 0, stream>>>(gc, gh);
    }
  }
}